// Round 2
// baseline (1255.596 us; speedup 1.0000x reference)
//
#include <hip/hip_runtime.h>
#include <cstdint>
#include <cstddef>

#define E_EXP 8
#define TOPK 2
#define DMODEL 512
#define DFFDIM 2048

typedef __attribute__((ext_vector_type(8))) short short8;
typedef __attribute__((ext_vector_type(4))) float f32x4;

__device__ __forceinline__ unsigned short f2bf(float f) {
    unsigned int u = __float_as_uint(f);
    u += 0x7fffu + ((u >> 16) & 1u);   // round-to-nearest-even
    return (unsigned short)(u >> 16);
}

__device__ __forceinline__ void gll16(const void* g, void* l) {
    __builtin_amdgcn_global_load_lds(
        (const __attribute__((address_space(1))) unsigned int*)g,
        (__attribute__((address_space(3))) unsigned int*)l, 16, 0, 0);
}

// ---------------- weight transpose + fp32->bf16 convert ----------------
// in: [E][R][C] fp32  ->  out: [E][C][R] bf16
__global__ __launch_bounds__(256) void transpose_kernel(
    const float* __restrict__ in, unsigned short* __restrict__ out, int R, int C)
{
    __shared__ float tile[32][33];
    const float* ie = in + (size_t)blockIdx.z * R * C;
    unsigned short* oe = out + (size_t)blockIdx.z * R * C;
    int x = blockIdx.x * 32 + threadIdx.x;
#pragma unroll
    for (int i = 0; i < 4; i++) {
        int ry = blockIdx.y * 32 + threadIdx.y + i * 8;
        tile[threadIdx.y + i * 8][threadIdx.x] = ie[(size_t)ry * C + x];
    }
    __syncthreads();
    int xo = blockIdx.y * 32 + threadIdx.x;
#pragma unroll
    for (int i = 0; i < 4; i++) {
        int co = blockIdx.x * 32 + threadIdx.y + i * 8;
        oe[(size_t)co * R + xo] = f2bf(tile[threadIdx.x][threadIdx.y + i * 8]);
    }
}

// ---------------- router: logits -> softmax -> top2 -> weights ----------------
__global__ __launch_bounds__(256) void router_kernel(
    const float* __restrict__ x, const float* __restrict__ Wr,
    const float* __restrict__ br, int N,
    int* __restrict__ e0e1, float2* __restrict__ w01)
{
    int lane = threadIdx.x & 63, wave = threadIdx.x >> 6;
    int t = blockIdx.x * 4 + wave;
    if (t >= N) return;
    const float* xr = x + (size_t)t * DMODEL;
    float4 v0 = *(const float4*)(xr + lane * 4);
    float4 v1 = *(const float4*)(xr + 256 + lane * 4);
    float xv[8] = {v0.x, v0.y, v0.z, v0.w, v1.x, v1.y, v1.z, v1.w};
    const float* wr0 = Wr + (size_t)lane * 32;             // rows lane*4 .. +3
    const float* wr1 = Wr + (size_t)(256 + lane * 4) * 8;  // rows 256+lane*4 .. +3
    double acc[8];
#pragma unroll
    for (int j = 0; j < 8; j++) acc[j] = 0.0;
#pragma unroll
    for (int c = 0; c < 4; c++) {
#pragma unroll
        for (int j = 0; j < 8; j++) {
            acc[j] += (double)xv[c] * (double)wr0[c * 8 + j];
            acc[j] += (double)xv[4 + c] * (double)wr1[c * 8 + j];
        }
    }
#pragma unroll
    for (int j = 0; j < 8; j++) {
        double s = acc[j];
#pragma unroll
        for (int o = 32; o > 0; o >>= 1) s += __shfl_xor(s, o, 64);
        acc[j] = s;
    }
    if (lane == 0) {
        float l[8], p[8];
        float mx = -1e30f;
        for (int j = 0; j < 8; j++) { l[j] = (float)acc[j] + br[j]; mx = fmaxf(mx, l[j]); }
        float Z = 0.f;
        for (int j = 0; j < 8; j++) { p[j] = expf(l[j] - mx); Z += p[j]; }
        for (int j = 0; j < 8; j++) p[j] /= Z;
        int e0 = 0;
        for (int j = 1; j < 8; j++) if (l[j] > l[e0]) e0 = j;        // ties -> lower idx
        int e1 = (e0 == 0) ? 1 : 0;
        for (int j = 0; j < 8; j++) if (j != e0 && l[j] > l[e1]) e1 = j;
        float den = p[e0] + p[e1] + 1e-9f;
        e0e1[t] = e0 | (e1 << 8);
        w01[t] = make_float2(p[e0] / den, p[e1] / den);
    }
}

// ---------------- per-block expert histogram (slot order) ----------------
__global__ __launch_bounds__(256) void hist_kernel(
    const int* __restrict__ e0e1, int NK, int* __restrict__ hist)
{
    __shared__ int cnt[8];
    int t = threadIdx.x;
    if (t < 8) cnt[t] = 0;
    __syncthreads();
    int s = blockIdx.x * 256 + t;
    if (s < NK) {
        int pk = e0e1[s >> 1];
        int e = (s & 1) ? ((pk >> 8) & 255) : (pk & 255);
        atomicAdd(&cnt[e], 1);
    }
    __syncthreads();
    if (t < 8) hist[blockIdx.x * 8 + t] = cnt[t];
}

// ---------------- scan histogram -> per-block bases + used counts ----------------
__global__ __launch_bounds__(256) void scan_kernel(
    const int* __restrict__ hist, int NB, int cap,
    int* __restrict__ base, int* __restrict__ cnt_used)
{
    __shared__ int buf[256];
    int t = threadIdx.x;
    for (int e = 0; e < 8; e++) {
        int v = (t < NB) ? hist[t * 8 + e] : 0;
        int val = v;
        buf[t] = val;
        __syncthreads();
        for (int o = 1; o < 256; o <<= 1) {
            int add = (t >= o) ? buf[t - o] : 0;
            __syncthreads();
            val += add;
            buf[t] = val;
            __syncthreads();
        }
        if (t < NB) base[t * 8 + e] = val - v;     // exclusive prefix
        if (t == 255) cnt_used[e] = min(val, cap); // total, clamped to capacity
        __syncthreads();
    }
}

// ---------------- positions, capacity drop, weight renorm, slot->token maps ----------------
__global__ __launch_bounds__(256) void pos_kernel(
    const int* __restrict__ e0e1, const float2* __restrict__ w01,
    const int* __restrict__ base, int NK, int cap,
    int* __restrict__ sidx, int* __restrict__ tok_of, float* __restrict__ wslot)
{
    __shared__ int waveCnt[4][8];
    __shared__ float kw[256];
    int t = threadIdx.x, lane = t & 63, wave = t >> 6;
    int s = blockIdx.x * 256 + t;
    bool valid = s < NK;
    int e = 8; float w = 0.f;
    if (valid) {
        int pk = e0e1[s >> 1];
        float2 ww = w01[s >> 1];
        if (s & 1) { e = (pk >> 8) & 255; w = ww.y; }
        else       { e = pk & 255;        w = ww.x; }
    }
    unsigned long long mymask = 0ull;
#pragma unroll
    for (int j = 0; j < 8; j++) {
        unsigned long long m = __ballot(e == j);
        if (lane == j) waveCnt[wave][j] = __popcll(m);
        if (e == j) mymask = m;
    }
    __syncthreads();
    int wrank = __popcll(mymask & ((1ull << lane) - 1ull));
    int prior = 0;
    for (int w2 = 0; w2 < wave; w2++) prior += waveCnt[w2][e & 7];
    int pos = base[blockIdx.x * 8 + (e & 7)] + prior + wrank;
    bool keep = valid && (pos < cap);
    kw[t] = keep ? w : 0.f;
    __syncthreads();
    float sum = kw[t] + kw[t ^ 1];      // the 2 slots of a token are adjacent
    float wn = keep ? (kw[t] / (sum + 1e-9f)) : 0.f;
    if (valid) {
        int si = keep ? (e * cap + pos) : -1;
        sidx[s] = si;
        if (keep) { tok_of[si] = s >> 1; wslot[si] = wn; }
    }
}

// ---------------- scatter tokens into expert buffers (fp32 -> bf16) ----------------
__global__ __launch_bounds__(256) void scatter_kernel(
    const float* __restrict__ x, const int* __restrict__ sidx,
    unsigned short* __restrict__ Xe, int NK)
{
    int lane = threadIdx.x & 63, wave = threadIdx.x >> 6;
    int s = blockIdx.x * 4 + wave;
    if (s >= NK) return;
    int si = sidx[s];
    if (si < 0) return;
    int tok = s >> 1;
    const float* xr = x + (size_t)tok * DMODEL + lane * 8;
    float4 a = *(const float4*)xr;
    float4 b = *(const float4*)(xr + 4);
    short8 v;
    v[0] = (short)f2bf(a.x); v[1] = (short)f2bf(a.y);
    v[2] = (short)f2bf(a.z); v[3] = (short)f2bf(a.w);
    v[4] = (short)f2bf(b.x); v[5] = (short)f2bf(b.y);
    v[6] = (short)f2bf(b.z); v[7] = (short)f2bf(b.w);
    *(short8*)(Xe + (size_t)si * DMODEL + lane * 8) = v;
}

// ---------------- grouped GEMM, m97 structure: 128x128 tile, BK=32 ----------------
// MODE 0: out(bf16 ushort) = GELU(A*B^T + bias), row stride ldc
// MODE 1: atomicAdd into y: y[tok_of[slot]] += wslot[slot] * (A*B^T + addB2?bias)
template <int MODE>
__global__ __launch_bounds__(256, 2) void gemm_kernel(
    const unsigned short* __restrict__ A, int lda, size_t aStrE,
    const unsigned short* __restrict__ B, int ldb, size_t bStrE,
    const float* __restrict__ bias, int biasStrE,
    void* __restrict__ out, size_t cStrE, int ldc,
    const int* __restrict__ cnt, const int* __restrict__ tok_of,
    const float* __restrict__ wslot, int cap, int Kext, int addB2)
{
    __shared__ unsigned short As[128 * 32];
    __shared__ unsigned short Bs[128 * 32];
    int e = blockIdx.z;
    int m0 = blockIdx.y * 128, n0 = blockIdx.x * 128;
    int M = cnt[e];
    if (m0 >= M) return;   // tile entirely beyond this expert's row count
    const unsigned short* Ae = A + (size_t)e * aStrE;
    const unsigned short* Be = B + (size_t)e * bStrE;

    int t = threadIdx.x, lane = t & 63, wave = t >> 6;
    int row = t >> 2, seg = (t & 3) * 8;                 // 4 x 16B segments per 64B k-row
    const unsigned short* ga = Ae + (size_t)(m0 + row) * lda + seg;
    const unsigned short* gb = Be + (size_t)(n0 + row) * ldb + seg;
    unsigned short* la0 = As + t * 8;
    unsigned short* la1 = As + (t + 256) * 8;
    unsigned short* lb0 = Bs + t * 8;
    unsigned short* lb1 = Bs + (t + 256) * 8;

    f32x4 acc[4][4];
#pragma unroll
    for (int i = 0; i < 4; i++)
#pragma unroll
        for (int j = 0; j < 4; j++) acc[i][j] = (f32x4){0.f, 0.f, 0.f, 0.f};

    int wm = (wave & 1) * 64, wn = (wave >> 1) * 64;
    int lr = lane & 15, lq = lane >> 4;
    const unsigned short* pa = As + (size_t)(wm + lr) * 32 + lq * 8;
    const unsigned short* pb = Bs + (size_t)(wn + lr) * 32 + lq * 8;

    for (int k0 = 0; k0 < Kext; k0 += 32) {
        gll16(ga, la0);
        gll16(ga + (size_t)64 * lda, la1);
        gll16(gb, lb0);
        gll16(gb + (size_t)64 * ldb, lb1);
        __syncthreads();          // drains vmcnt -> staging visible
        short8 af[4], bf[4];
#pragma unroll
        for (int i = 0; i < 4; i++) af[i] = *(const short8*)(pa + i * 16 * 32);
#pragma unroll
        for (int j = 0; j < 4; j++) bf[j] = *(const short8*)(pb + j * 16 * 32);
#pragma unroll
        for (int i = 0; i < 4; i++)
#pragma unroll
            for (int j = 0; j < 4; j++)
                acc[i][j] = __builtin_amdgcn_mfma_f32_16x16x32_bf16(af[i], bf[j], acc[i][j], 0, 0, 0);
        __syncthreads();          // LDS reuse fence
        ga += 32; gb += 32;
    }

    // epilogue; C/D layout: col=lane&15, row=(lane>>4)*4+r
    if (MODE == 0) {
        size_t cb = (size_t)e * cStrE;
#pragma unroll
        for (int j = 0; j < 4; j++) {
            int n = n0 + wn + j * 16 + lr;
            float bv = bias[(size_t)e * biasStrE + n];
#pragma unroll
            for (int i = 0; i < 4; i++) {
                int mbase = m0 + wm + i * 16 + lq * 4;
                f32x4 v = acc[i][j];
#pragma unroll
                for (int r = 0; r < 4; r++) {
                    float val = v[r] + bv;
                    val = 0.5f * val * (1.0f + erff(val * 0.7071067811865475f));
                    ((unsigned short*)out)[cb + (size_t)(mbase + r) * ldc + n] = f2bf(val);
                }
            }
        }
    } else {
        float wv[4][4]; int tv[4][4];
#pragma unroll
        for (int i = 0; i < 4; i++) {
            int mbase = m0 + wm + i * 16 + lq * 4;
#pragma unroll
            for (int r = 0; r < 4; r++) {
                int m = mbase + r;
                if (m < M) { int sl = e * cap + m; wv[i][r] = wslot[sl]; tv[i][r] = tok_of[sl]; }
                else       { wv[i][r] = 0.f; tv[i][r] = -1; }
            }
        }
        float* y = (float*)out;
#pragma unroll
        for (int j = 0; j < 4; j++) {
            int n = n0 + wn + j * 16 + lr;
            float bv = addB2 ? bias[(size_t)e * biasStrE + n] : 0.f;
#pragma unroll
            for (int i = 0; i < 4; i++) {
                f32x4 v = acc[i][j];
#pragma unroll
                for (int r = 0; r < 4; r++) {
                    if (tv[i][r] >= 0)
                        atomicAdd(y + (size_t)tv[i][r] * ldc + n, wv[i][r] * (v[r] + bv));
                }
            }
        }
    }
}

extern "C" void kernel_launch(void* const* d_in, const int* in_sizes, int n_in,
                              void* d_out, int out_size, void* d_ws, size_t ws_size,
                              hipStream_t stream)
{
    const float* x  = (const float*)d_in[0];
    const float* Wr = (const float*)d_in[1];
    const float* br = (const float*)d_in[2];
    const float* W1 = (const float*)d_in[3];
    const float* b1 = (const float*)d_in[4];
    const float* W2 = (const float*)d_in[5];
    const float* b2 = (const float*)d_in[6];
    float* y = (float*)d_out;
    (void)n_in;

    const int N = in_sizes[0] / DMODEL;            // 32768 tokens
    const int NK = N * TOPK;                       // 65536 slots
    const int cap = (NK * 5 + 31) / 32;            // ceil(1.25*NK/8) = 10240
    const int mTiles = (cap + 127) / 128;          // 80
    const int NB = (NK + 255) / 256;               // 256

    // fixed buffers: W1t 16M + W2t 16M + Xe 80M + ~1.4M small
    size_t fixed = (size_t)E_EXP * DMODEL * DFFDIM * 2 * 2
                 + (size_t)E_EXP * cap * DMODEL * 2
                 + (size_t)N * 12 + (size_t)NK * 4 + (size_t)E_EXP * cap * 8
                 + (size_t)NB * 64 + (1 << 16);
    // pick largest DFF chunk F whose H-chunk buffer fits ws_size (F constant across calls)
    int F = DFFDIM;
    while (F > 256 && fixed + (size_t)E_EXP * cap * F * 2 > ws_size) F >>= 1;
    const int nChunks = DFFDIM / F;

    char* ws = (char*)d_ws;
    size_t off = 0;
    auto take = [&](size_t bytes) {
        char* p = ws + off;
        off = (off + bytes + 255) & ~(size_t)255;
        return p;
    };
    unsigned short* W1t = (unsigned short*)take((size_t)E_EXP * DMODEL * DFFDIM * 2); // [E][DFF][D]
    unsigned short* W2t = (unsigned short*)take((size_t)E_EXP * DMODEL * DFFDIM * 2); // [E][D][DFF]
    unsigned short* Xe  = (unsigned short*)take((size_t)E_EXP * cap * DMODEL * 2);    // expert_in bf16
    unsigned short* Hc  = (unsigned short*)take((size_t)E_EXP * cap * F * 2);         // hidden chunk bf16
    int*    e0e1 = (int*)take((size_t)N * 4);
    float2* w01  = (float2*)take((size_t)N * 8);
    int*    hist = (int*)take((size_t)NB * 8 * 4);
    int*    base = (int*)take((size_t)NB * 8 * 4);
    int*    cnt  = (int*)take(64);
    int*    sidx = (int*)take((size_t)NK * 4);
    int*    tok_of = (int*)take((size_t)E_EXP * cap * 4);
    float*  wslot  = (float*)take((size_t)E_EXP * cap * 4);

    transpose_kernel<<<dim3(DFFDIM / 32, DMODEL / 32, E_EXP), dim3(32, 8), 0, stream>>>(W1, W1t, DMODEL, DFFDIM);
    transpose_kernel<<<dim3(DMODEL / 32, DFFDIM / 32, E_EXP), dim3(32, 8), 0, stream>>>(W2, W2t, DFFDIM, DMODEL);
    router_kernel<<<(N + 3) / 4, 256, 0, stream>>>(x, Wr, br, N, e0e1, w01);
    hist_kernel<<<NB, 256, 0, stream>>>(e0e1, NK, hist);
    scan_kernel<<<1, 256, 0, stream>>>(hist, NB, cap, base, cnt);
    pos_kernel<<<NB, 256, 0, stream>>>(e0e1, w01, base, NK, cap, sidx, tok_of, wslot);
    scatter_kernel<<<(NK + 3) / 4, 256, 0, stream>>>(x, sidx, Xe, NK);
    hipMemsetAsync(d_out, 0, (size_t)out_size * 4, stream);

    for (int c = 0; c < nChunks; c++) {
        // GEMM1 chunk: Hc = GELU(Xe[cap x 512] * W1t_chunk[F x 512]^T + b1_chunk)
        gemm_kernel<0><<<dim3(F / 128, mTiles, E_EXP), 256, 0, stream>>>(
            Xe, DMODEL, (size_t)cap * DMODEL,
            W1t + (size_t)c * F * DMODEL, DMODEL, (size_t)DFFDIM * DMODEL,
            b1 + (size_t)c * F, DFFDIM,
            Hc, (size_t)cap * F, F,
            cnt, tok_of, wslot, cap, DMODEL, 0);
        // GEMM2 chunk: y += wslot * (Hc[cap x F] * W2t[:, chunk][512 x F]^T (+ b2 on c==0))
        gemm_kernel<1><<<dim3(DMODEL / 128, mTiles, E_EXP), 256, 0, stream>>>(
            Hc, F, (size_t)cap * F,
            W2t + (size_t)c * F, DFFDIM, (size_t)DMODEL * DFFDIM,
            b2, DMODEL,
            y, 0, DMODEL,
            cnt, tok_of, wslot, cap, F, c == 0);
    }
}

// Round 3
// 992.745 us; speedup vs baseline: 1.2648x; 1.2648x over previous
//
#include <hip/hip_runtime.h>
#include <cstdint>
#include <cstddef>

#define E_EXP 8
#define TOPK 2
#define DMODEL 512
#define DFFDIM 2048

typedef __attribute__((ext_vector_type(8))) short short8;
typedef __attribute__((ext_vector_type(4))) float f32x4;

__device__ __forceinline__ unsigned short f2bf(float f) {
    unsigned int u = __float_as_uint(f);
    u += 0x7fffu + ((u >> 16) & 1u);   // round-to-nearest-even
    return (unsigned short)(u >> 16);
}

// ---------------- weight transpose + fp32->bf16 convert ----------------
// in: [E][R][C] fp32  ->  out: [E][C][R] bf16
__global__ __launch_bounds__(256) void transpose_kernel(
    const float* __restrict__ in, unsigned short* __restrict__ out, int R, int C)
{
    __shared__ float tile[32][33];
    const float* ie = in + (size_t)blockIdx.z * R * C;
    unsigned short* oe = out + (size_t)blockIdx.z * R * C;
    int x = blockIdx.x * 32 + threadIdx.x;
#pragma unroll
    for (int i = 0; i < 4; i++) {
        int ry = blockIdx.y * 32 + threadIdx.y + i * 8;
        tile[threadIdx.y + i * 8][threadIdx.x] = ie[(size_t)ry * C + x];
    }
    __syncthreads();
    int xo = blockIdx.y * 32 + threadIdx.x;
#pragma unroll
    for (int i = 0; i < 4; i++) {
        int co = blockIdx.x * 32 + threadIdx.y + i * 8;
        oe[(size_t)co * R + xo] = f2bf(tile[threadIdx.x][threadIdx.y + i * 8]);
    }
}

// ---------------- router: logits -> softmax -> top2 -> weights ----------------
__global__ __launch_bounds__(256) void router_kernel(
    const float* __restrict__ x, const float* __restrict__ Wr,
    const float* __restrict__ br, int N,
    int* __restrict__ e0e1, float2* __restrict__ w01)
{
    int lane = threadIdx.x & 63, wave = threadIdx.x >> 6;
    int t = blockIdx.x * 4 + wave;
    if (t >= N) return;
    const float* xr = x + (size_t)t * DMODEL;
    float4 v0 = *(const float4*)(xr + lane * 4);
    float4 v1 = *(const float4*)(xr + 256 + lane * 4);
    float xv[8] = {v0.x, v0.y, v0.z, v0.w, v1.x, v1.y, v1.z, v1.w};
    const float* wr0 = Wr + (size_t)lane * 32;             // rows lane*4 .. +3
    const float* wr1 = Wr + (size_t)(256 + lane * 4) * 8;  // rows 256+lane*4 .. +3
    double acc[8];
#pragma unroll
    for (int j = 0; j < 8; j++) acc[j] = 0.0;
#pragma unroll
    for (int c = 0; c < 4; c++) {
#pragma unroll
        for (int j = 0; j < 8; j++) {
            acc[j] += (double)xv[c] * (double)wr0[c * 8 + j];
            acc[j] += (double)xv[4 + c] * (double)wr1[c * 8 + j];
        }
    }
#pragma unroll
    for (int j = 0; j < 8; j++) {
        double s = acc[j];
#pragma unroll
        for (int o = 32; o > 0; o >>= 1) s += __shfl_xor(s, o, 64);
        acc[j] = s;
    }
    if (lane == 0) {
        float l[8], p[8];
        float mx = -1e30f;
        for (int j = 0; j < 8; j++) { l[j] = (float)acc[j] + br[j]; mx = fmaxf(mx, l[j]); }
        float Z = 0.f;
        for (int j = 0; j < 8; j++) { p[j] = expf(l[j] - mx); Z += p[j]; }
        for (int j = 0; j < 8; j++) p[j] /= Z;
        int e0 = 0;
        for (int j = 1; j < 8; j++) if (l[j] > l[e0]) e0 = j;        // ties -> lower idx
        int e1 = (e0 == 0) ? 1 : 0;
        for (int j = 0; j < 8; j++) if (j != e0 && l[j] > l[e1]) e1 = j;
        float den = p[e0] + p[e1] + 1e-9f;
        e0e1[t] = e0 | (e1 << 8);
        w01[t] = make_float2(p[e0] / den, p[e1] / den);
    }
}

// ---------------- per-block expert histogram (slot order) ----------------
__global__ __launch_bounds__(256) void hist_kernel(
    const int* __restrict__ e0e1, int NK, int* __restrict__ hist)
{
    __shared__ int cnt[8];
    int t = threadIdx.x;
    if (t < 8) cnt[t] = 0;
    __syncthreads();
    int s = blockIdx.x * 256 + t;
    if (s < NK) {
        int pk = e0e1[s >> 1];
        int e = (s & 1) ? ((pk >> 8) & 255) : (pk & 255);
        atomicAdd(&cnt[e], 1);
    }
    __syncthreads();
    if (t < 8) hist[blockIdx.x * 8 + t] = cnt[t];
}

// ---------------- scan histogram -> per-block bases + used counts ----------------
__global__ __launch_bounds__(256) void scan_kernel(
    const int* __restrict__ hist, int NB, int cap,
    int* __restrict__ base, int* __restrict__ cnt_used)
{
    __shared__ int buf[256];
    int t = threadIdx.x;
    for (int e = 0; e < 8; e++) {
        int v = (t < NB) ? hist[t * 8 + e] : 0;
        int val = v;
        buf[t] = val;
        __syncthreads();
        for (int o = 1; o < 256; o <<= 1) {
            int add = (t >= o) ? buf[t - o] : 0;
            __syncthreads();
            val += add;
            buf[t] = val;
            __syncthreads();
        }
        if (t < NB) base[t * 8 + e] = val - v;     // exclusive prefix
        if (t == 255) cnt_used[e] = min(val, cap); // total, clamped to capacity
        __syncthreads();
    }
}

// ---------------- positions, capacity drop, weight renorm, slot->token maps ----------------
__global__ __launch_bounds__(256) void pos_kernel(
    const int* __restrict__ e0e1, const float2* __restrict__ w01,
    const int* __restrict__ base, int NK, int cap,
    int* __restrict__ sidx, int* __restrict__ tok_of, float* __restrict__ wslot)
{
    __shared__ int waveCnt[4][8];
    __shared__ float kw[256];
    int t = threadIdx.x, lane = t & 63, wave = t >> 6;
    int s = blockIdx.x * 256 + t;
    bool valid = s < NK;
    int e = 8; float w = 0.f;
    if (valid) {
        int pk = e0e1[s >> 1];
        float2 ww = w01[s >> 1];
        if (s & 1) { e = (pk >> 8) & 255; w = ww.y; }
        else       { e = pk & 255;        w = ww.x; }
    }
    unsigned long long mymask = 0ull;
#pragma unroll
    for (int j = 0; j < 8; j++) {
        unsigned long long m = __ballot(e == j);
        if (lane == j) waveCnt[wave][j] = __popcll(m);
        if (e == j) mymask = m;
    }
    __syncthreads();
    int wrank = __popcll(mymask & ((1ull << lane) - 1ull));
    int prior = 0;
    for (int w2 = 0; w2 < wave; w2++) prior += waveCnt[w2][e & 7];
    int pos = base[blockIdx.x * 8 + (e & 7)] + prior + wrank;
    bool keep = valid && (pos < cap);
    kw[t] = keep ? w : 0.f;
    __syncthreads();
    float sum = kw[t] + kw[t ^ 1];      // the 2 slots of a token are adjacent
    float wn = keep ? (kw[t] / (sum + 1e-9f)) : 0.f;
    if (valid) {
        int si = keep ? (e * cap + pos) : -1;
        sidx[s] = si;
        if (keep) { tok_of[si] = s >> 1; wslot[si] = wn; }
    }
}

// ---------------- scatter tokens into expert buffers (fp32 -> bf16) ----------------
__global__ __launch_bounds__(256) void scatter_kernel(
    const float* __restrict__ x, const int* __restrict__ sidx,
    unsigned short* __restrict__ Xe, int NK)
{
    int lane = threadIdx.x & 63, wave = threadIdx.x >> 6;
    int s = blockIdx.x * 4 + wave;
    if (s >= NK) return;
    int si = sidx[s];
    if (si < 0) return;
    int tok = s >> 1;
    const float* xr = x + (size_t)tok * DMODEL + lane * 8;
    float4 a = *(const float4*)xr;
    float4 b = *(const float4*)(xr + 4);
    short8 v;
    v[0] = (short)f2bf(a.x); v[1] = (short)f2bf(a.y);
    v[2] = (short)f2bf(a.z); v[3] = (short)f2bf(a.w);
    v[4] = (short)f2bf(b.x); v[5] = (short)f2bf(b.y);
    v[6] = (short)f2bf(b.z); v[7] = (short)f2bf(b.w);
    *(short8*)(Xe + (size_t)si * DMODEL + lane * 8) = v;
}

// ---------------- grouped GEMM: 128x128 tile, BK=32, reg-staged double-buffered LDS ----
// MODE 0: out(bf16 ushort) = GELU(A*B^T + bias), row stride ldc
// MODE 1: atomicAdd into y: y[tok_of[slot]] += wslot[slot] * (A*B^T + bias)
template <int MODE>
__global__ __launch_bounds__(256, 3) void gemm_kernel(
    const unsigned short* __restrict__ A, int lda, size_t aStrE,
    const unsigned short* __restrict__ B, int ldb, size_t bStrE,
    const float* __restrict__ bias, int biasStrE,
    void* __restrict__ out, size_t cStrE, int ldc,
    const int* __restrict__ cnt, const int* __restrict__ tok_of,
    const float* __restrict__ wslot, int cap, int Kext)
{
    __shared__ unsigned short As[2][128 * 32];
    __shared__ unsigned short Bs[2][128 * 32];
    int e = blockIdx.z;
    int m0 = blockIdx.y * 128, n0 = blockIdx.x * 128;
    int M = cnt[e];
    if (m0 >= M) return;   // tile entirely beyond this expert's row count
    const unsigned short* Ae = A + (size_t)e * aStrE;
    const unsigned short* Be = B + (size_t)e * bStrE;

    int t = threadIdx.x, lane = t & 63, wave = t >> 6;
    int row = t >> 2, seg = (t & 3) * 8;                 // 4 x 16B segments per 64B k-row
    const unsigned short* ga = Ae + (size_t)(m0 + row) * lda + seg;
    const unsigned short* gb = Be + (size_t)(n0 + row) * ldb + seg;
    unsigned short* la0 = &As[0][t * 8];
    unsigned short* la1 = &As[0][(t + 256) * 8];
    unsigned short* lb0 = &Bs[0][t * 8];
    unsigned short* lb1 = &Bs[0][(t + 256) * 8];

    f32x4 acc[4][4];
#pragma unroll
    for (int i = 0; i < 4; i++)
#pragma unroll
        for (int j = 0; j < 4; j++) acc[i][j] = (f32x4){0.f, 0.f, 0.f, 0.f};

    int wm = (wave & 1) * 64, wn = (wave >> 1) * 64;
    int lr = lane & 15, lq = lane >> 4;
    const unsigned short* pa = &As[0][(wm + lr) * 32 + lq * 8];
    const unsigned short* pb = &Bs[0][(wn + lr) * 32 + lq * 8];

    // prologue: stage k-tile 0 into buf 0
    short8 ra0 = *(const short8*)ga;
    short8 ra1 = *(const short8*)(ga + (size_t)64 * lda);
    short8 rb0 = *(const short8*)gb;
    short8 rb1 = *(const short8*)(gb + (size_t)64 * ldb);
    ga += 32; gb += 32;
    *(short8*)la0 = ra0; *(short8*)la1 = ra1;
    *(short8*)lb0 = rb0; *(short8*)lb1 = rb1;
    __syncthreads();

    int buf = 0;
    for (int k0 = 32; k0 < Kext; k0 += 32) {
        // prefetch next k-tile into registers (latency overlapped with compute below)
        ra0 = *(const short8*)ga;
        ra1 = *(const short8*)(ga + (size_t)64 * lda);
        rb0 = *(const short8*)gb;
        rb1 = *(const short8*)(gb + (size_t)64 * ldb);
        ga += 32; gb += 32;
        // compute from current buffer
        {
            int bo = buf * (128 * 32);
            short8 af[4], bf[4];
#pragma unroll
            for (int i = 0; i < 4; i++) af[i] = *(const short8*)(pa + bo + i * 16 * 32);
#pragma unroll
            for (int j = 0; j < 4; j++) bf[j] = *(const short8*)(pb + bo + j * 16 * 32);
#pragma unroll
            for (int i = 0; i < 4; i++)
#pragma unroll
                for (int j = 0; j < 4; j++)
                    acc[i][j] = __builtin_amdgcn_mfma_f32_16x16x32_bf16(af[i], bf[j], acc[i][j], 0, 0, 0);
        }
        // write next buffer (vmcnt wait lands here, after the MFMAs)
        int nbo = (buf ^ 1) * (128 * 32);
        *(short8*)(la0 + nbo) = ra0; *(short8*)(la1 + nbo) = ra1;
        *(short8*)(lb0 + nbo) = rb0; *(short8*)(lb1 + nbo) = rb1;
        __syncthreads();
        buf ^= 1;
    }
    // last k-tile compute
    {
        int bo = buf * (128 * 32);
        short8 af[4], bf[4];
#pragma unroll
        for (int i = 0; i < 4; i++) af[i] = *(const short8*)(pa + bo + i * 16 * 32);
#pragma unroll
        for (int j = 0; j < 4; j++) bf[j] = *(const short8*)(pb + bo + j * 16 * 32);
#pragma unroll
        for (int i = 0; i < 4; i++)
#pragma unroll
            for (int j = 0; j < 4; j++)
                acc[i][j] = __builtin_amdgcn_mfma_f32_16x16x32_bf16(af[i], bf[j], acc[i][j], 0, 0, 0);
    }

    // epilogue; C/D layout: col=lane&15, row=(lane>>4)*4+r
    if (MODE == 0) {
        size_t cb = (size_t)e * cStrE;
#pragma unroll
        for (int j = 0; j < 4; j++) {
            int n = n0 + wn + j * 16 + lr;
            float bv = bias[(size_t)e * biasStrE + n];
#pragma unroll
            for (int i = 0; i < 4; i++) {
                int mbase = m0 + wm + i * 16 + lq * 4;
                f32x4 v = acc[i][j];
#pragma unroll
                for (int r = 0; r < 4; r++) {
                    float val = v[r] + bv;
                    val = 0.5f * val * (1.0f + erff(val * 0.7071067811865475f));
                    ((unsigned short*)out)[cb + (size_t)(mbase + r) * ldc + n] = f2bf(val);
                }
            }
        }
    } else {
        float wv[4][4]; int tv[4][4];
#pragma unroll
        for (int i = 0; i < 4; i++) {
            int mbase = m0 + wm + i * 16 + lq * 4;
#pragma unroll
            for (int r = 0; r < 4; r++) {
                int m = mbase + r;
                if (m < M) { int sl = e * cap + m; wv[i][r] = wslot[sl]; tv[i][r] = tok_of[sl]; }
                else       { wv[i][r] = 0.f; tv[i][r] = -1; }
            }
        }
        float* y = (float*)out;
#pragma unroll
        for (int j = 0; j < 4; j++) {
            int n = n0 + wn + j * 16 + lr;
            float bv = bias[(size_t)e * biasStrE + n];
#pragma unroll
            for (int i = 0; i < 4; i++) {
                f32x4 v = acc[i][j];
#pragma unroll
                for (int r = 0; r < 4; r++) {
                    if (tv[i][r] >= 0)
                        atomicAdd(y + (size_t)tv[i][r] * ldc + n, wv[i][r] * (v[r] + bv));
                }
            }
        }
    }
}

extern "C" void kernel_launch(void* const* d_in, const int* in_sizes, int n_in,
                              void* d_out, int out_size, void* d_ws, size_t ws_size,
                              hipStream_t stream)
{
    const float* x  = (const float*)d_in[0];
    const float* Wr = (const float*)d_in[1];
    const float* br = (const float*)d_in[2];
    const float* W1 = (const float*)d_in[3];
    const float* b1 = (const float*)d_in[4];
    const float* W2 = (const float*)d_in[5];
    const float* b2 = (const float*)d_in[6];
    float* y = (float*)d_out;
    (void)n_in;

    const int N = in_sizes[0] / DMODEL;            // 32768 tokens
    const int NK = N * TOPK;                       // 65536 slots
    const int cap = (NK * 5 + 31) / 32;            // ceil(1.25*NK/8) = 10240
    const int mTiles = (cap + 127) / 128;          // 80
    const int NB = (NK + 255) / 256;               // 256

    // fixed buffers (no H): W1t 16M + W2t 16M + Xe 84M + ~1.5M small
    size_t fixed = (size_t)E_EXP * DMODEL * DFFDIM * 2 * 2
                 + (size_t)E_EXP * cap * DMODEL * 2
                 + (size_t)N * 12 + (size_t)NK * 4 + (size_t)E_EXP * cap * 8
                 + (size_t)NB * 64 + (1 << 16);
    // experts per group G: largest whose H-group buffer fits ws (constant across calls)
    int G = E_EXP;
    while (G > 1 && fixed + (size_t)G * cap * DFFDIM * 2 > ws_size) G >>= 1;
    const int nGroups = E_EXP / G;

    char* ws = (char*)d_ws;
    size_t off = 0;
    auto take = [&](size_t bytes) {
        char* p = ws + off;
        off = (off + bytes + 255) & ~(size_t)255;
        return p;
    };
    unsigned short* W1t = (unsigned short*)take((size_t)E_EXP * DMODEL * DFFDIM * 2); // [E][DFF][D]
    unsigned short* W2t = (unsigned short*)take((size_t)E_EXP * DMODEL * DFFDIM * 2); // [E][D][DFF]
    unsigned short* Xe  = (unsigned short*)take((size_t)E_EXP * cap * DMODEL * 2);    // expert_in bf16
    unsigned short* Hg  = (unsigned short*)take((size_t)G * cap * DFFDIM * 2);        // hidden, G experts
    int*    e0e1 = (int*)take((size_t)N * 4);
    float2* w01  = (float2*)take((size_t)N * 8);
    int*    hist = (int*)take((size_t)NB * 8 * 4);
    int*    base = (int*)take((size_t)NB * 8 * 4);
    int*    cnt  = (int*)take(64);
    int*    sidx = (int*)take((size_t)NK * 4);
    int*    tok_of = (int*)take((size_t)E_EXP * cap * 4);
    float*  wslot  = (float*)take((size_t)E_EXP * cap * 4);

    transpose_kernel<<<dim3(DFFDIM / 32, DMODEL / 32, E_EXP), dim3(32, 8), 0, stream>>>(W1, W1t, DMODEL, DFFDIM);
    transpose_kernel<<<dim3(DMODEL / 32, DFFDIM / 32, E_EXP), dim3(32, 8), 0, stream>>>(W2, W2t, DFFDIM, DMODEL);
    router_kernel<<<(N + 3) / 4, 256, 0, stream>>>(x, Wr, br, N, e0e1, w01);
    hist_kernel<<<NB, 256, 0, stream>>>(e0e1, NK, hist);
    scan_kernel<<<1, 256, 0, stream>>>(hist, NB, cap, base, cnt);
    pos_kernel<<<NB, 256, 0, stream>>>(e0e1, w01, base, NK, cap, sidx, tok_of, wslot);
    scatter_kernel<<<(NK + 3) / 4, 256, 0, stream>>>(x, sidx, Xe, NK);
    hipMemsetAsync(d_out, 0, (size_t)out_size * 4, stream);

    for (int g = 0; g < nGroups; g++) {
        int e0 = g * G;
        // GEMM1: Hg[e] = GELU(Xe[e] * W1t[e]^T + b1[e])  for e in group, K=512
        gemm_kernel<0><<<dim3(DFFDIM / 128, mTiles, G), 256, 0, stream>>>(
            Xe + (size_t)e0 * cap * DMODEL, DMODEL, (size_t)cap * DMODEL,
            W1t + (size_t)e0 * DFFDIM * DMODEL, DMODEL, (size_t)DFFDIM * DMODEL,
            b1 + (size_t)e0 * DFFDIM, DFFDIM,
            Hg, (size_t)cap * DFFDIM, DFFDIM,
            cnt + e0, tok_of, wslot, cap, DMODEL);
        // GEMM2: y[tok] += wslot * (Hg[e] * W2t[e]^T + b2[e]),  K=2048
        gemm_kernel<1><<<dim3(DMODEL / 128, mTiles, G), 256, 0, stream>>>(
            Hg, DFFDIM, (size_t)cap * DFFDIM,
            W2t + (size_t)e0 * DMODEL * DFFDIM, DFFDIM, (size_t)DMODEL * DFFDIM,
            b2 + (size_t)e0 * DMODEL, DMODEL,
            y, 0, DMODEL,
            cnt + e0, tok_of + (size_t)e0 * cap, wslot + (size_t)e0 * cap, cap, DFFDIM);
    }
}